// Round 8
// baseline (309.903 us; speedup 1.0000x reference)
//
#include <hip/hip_runtime.h>

// Problem: N=4096, D=1024, C=1000, T=32
//   h = x @ W^T  (4096 x 2000), mu = h[:, :1000], logvar = h[:, 1000:]
//   sigma = exp(0.5*logvar)
//   eps = jax.random.normal(key(42), (32,4096,1000))  -- threefry2x32, bit-exact
//   prob = mean_t softmax(mu + sigma*eps), out0 = exp(prob), out1 = sigma
//
// r16: overlap the mu/sigma-INDEPENDENT part of sampling (threefry->erfinv, ~75% of
// sample's VALU work) with the MFMA-bound GEMM. Odd blocks of the gemm launch are RNG
// workers precomputing epsp for the it==0 quarter (t in {0,4,8,12} pairs), stored as
// exact f32 (bit-identical). m114: MFMA-waves and VALU-waves co-schedule at ~max.
// ws-guarded: pre=0 falls back to the r6 known-good path.

typedef __attribute__((ext_vector_type(8))) _Float16 f16x8;
typedef __attribute__((ext_vector_type(4))) float f32x4;
typedef __attribute__((ext_vector_type(2))) float f32x2;

#define NC_TOT  4096000
#define H_HALF  65536000u   // half of T*N*C = 131072000
#define EPS2_OFF 28966912u  // byte offset of eps2 in ws (after xh/wh/mu)
#define WS_NEED  163184640u // EPS2_OFF + 4*4096*1024*8

// ---------------- fp32 -> fp16 (RNE) ----------------
__device__ __forceinline__ unsigned short f2h(float f) {
  _Float16 h = (_Float16)f;
  return __builtin_bit_cast(unsigned short, h);
}

__global__ __launch_bounds__(256) void convert_kernel(
    const float* __restrict__ x, const float* __restrict__ W,
    unsigned short* __restrict__ xh, unsigned short* __restrict__ wh) {
  int qid = blockIdx.x * 256 + threadIdx.x;
  if (qid < 1048576) {                        // x: 4096*1024/4
    float4 v = ((const float4*)x)[qid];
    ((ushort4*)xh)[qid] = make_ushort4(f2h(v.x), f2h(v.y), f2h(v.z), f2h(v.w));
  } else {
    int q = qid - 1048576;                    // padded W quad index, < 524288
    int row = q >> 8;
    ushort4 o;
    if (row < 2000) {
      float4 v = ((const float4*)W)[q];
      o = make_ushort4(f2h(v.x), f2h(v.y), f2h(v.z), f2h(v.w));
    } else {
      o = make_ushort4(0, 0, 0, 0);
    }
    ((ushort4*)wh)[q] = o;
  }
}

// ---------------- threefry2x32, key = (0, 42) ----------------
// rotl forced to single v_alignbit_b32 (rotl(x,r) == rotr(x,32-r)).
__device__ __forceinline__ unsigned rotl_(unsigned x, unsigned r) {
  return __builtin_amdgcn_alignbit(x, x, 32u - r);
}

__device__ __forceinline__ void threefry(unsigned x0, unsigned x1,
                                         unsigned& o0, unsigned& o1) {
  const unsigned ks1 = 42u;
  const unsigned ks2 = 0x1BD11BDAu ^ 42u;
#define TF_RND(r) { x0 += x1; x1 = rotl_(x1, r); x1 ^= x0; }
  x1 += ks1;
  TF_RND(13) TF_RND(15) TF_RND(26) TF_RND(6)
  x0 += ks1;  x1 += ks2 + 1u;
  TF_RND(17) TF_RND(29) TF_RND(16) TF_RND(24)
  x0 += ks2;  x1 += 2u;
  TF_RND(13) TF_RND(15) TF_RND(26) TF_RND(6)
  x1 += ks1 + 3u;
  TF_RND(17) TF_RND(29) TF_RND(16) TF_RND(24)
  x0 += ks1;  x1 += ks2 + 4u;
  TF_RND(13) TF_RND(15) TF_RND(26) TF_RND(6)
  x0 += ks2;  x1 += 5u;
#undef TF_RND
  o0 = x0; o1 = x1;
}

__device__ __forceinline__ f32x2 splat2(float c) { return (f32x2){c, c}; }

// Tail branch of erfinv; returns p*x WITHOUT the sqrt2 factor
// (sqrt2*log2e is folded into the precomputed sigma scale).
__device__ __forceinline__ float erfinv_big_p(float x, float lg) {
  float w = lg * -0.69314718f;
  float v = __fsqrt_rn(w) - 3.0f;
  float p = -0.000200214257f;
  p = fmaf(p, v, 0.000100950558f);
  p = fmaf(p, v, 0.00134934322f);
  p = fmaf(p, v, -0.00367342844f);
  p = fmaf(p, v, 0.00573950773f);
  p = fmaf(p, v, -0.0076224613f);
  p = fmaf(p, v, 0.00943887047f);
  p = fmaf(p, v, 1.00167406f);
  p = fmaf(p, v, 2.83297682f);
  return p * x;
}

// normal WITHOUT the sqrt2 factor: returns p(v)*x (r6 verbatim, passing).
__device__ __forceinline__ f32x2 normal2p(f32x2 x) {
  f32x2 t = __builtin_elementwise_fma(-x, x, splat2(1.0f));
  f32x2 lg;
  lg.x = __builtin_amdgcn_logf(t.x);
  lg.y = __builtin_amdgcn_logf(t.y);
  f32x2 v = __builtin_elementwise_fma(lg, splat2(-0.69314718f), splat2(-2.5f));
  f32x2 p = splat2(2.81022636e-08f);
  p = __builtin_elementwise_fma(p, v, splat2(3.43273939e-07f));
  p = __builtin_elementwise_fma(p, v, splat2(-3.5233877e-06f));
  p = __builtin_elementwise_fma(p, v, splat2(-4.39150654e-06f));
  p = __builtin_elementwise_fma(p, v, splat2(0.00021858087f));
  p = __builtin_elementwise_fma(p, v, splat2(-0.00125372503f));
  p = __builtin_elementwise_fma(p, v, splat2(-0.00417768164f));
  p = __builtin_elementwise_fma(p, v, splat2(0.246640727f));
  p = __builtin_elementwise_fma(p, v, splat2(1.50140941f));
  f32x2 r = p * x;
  bool c0 = lg.x <= -7.2134752f;                 // == (w >= 5), rare (~0.34%/sample)
  bool c1 = lg.y <= -7.2134752f;
  if (__builtin_expect(__ballot(c0 || c1) != 0ull, false)) {
    if (c0) r.x = erfinv_big_p(x.x, lg.x);
    if (c1) r.y = erfinv_big_p(x.y, lg.y);
  }
  return r;
}

__device__ __forceinline__ f32x2 bits_to_u2(unsigned b0, unsigned b1) {
  f32x2 f;
  f.x = __builtin_bit_cast(float, (b0 >> 9) | 0x3f800000u);
  f.y = __builtin_bit_cast(float, (b1 >> 9) | 0x3f800000u);
  f = f - splat2(1.0f);
  return __builtin_elementwise_fma(f, splat2(2.0f), splat2(-0.99999994f));
}

// ---------------- fused fp16 MFMA GEMM (even blocks) + RNG precompute (odd) ---------
// GEMM body is the r3/r6 verbatim known-good loop. RNG blocks write epsp for
// t = 4*w (it==0) as f32x2 at eps2[(w*4096 + n)*1024 + j*64 + lane] (nontemporal,
// 512B/wave contiguous). Interleaved ids -> ~2 GEMM + 2 RNG blocks co-resident per CU.
#define BK 32

typedef __attribute__((address_space(3))) unsigned char lds_byte;
typedef __attribute__((address_space(1))) unsigned char glb_byte;

__device__ __forceinline__ void glds16(const unsigned short* g, unsigned short* l) {
  __builtin_amdgcn_global_load_lds((const glb_byte*)g, (lds_byte*)l, 16, 0, 0);
}

__global__ __launch_bounds__(256) void gemm_rng_kernel(
    const unsigned short* __restrict__ Ah,    // [4096][1024] fp16 bits
    const unsigned short* __restrict__ Bh,    // [2048][1024] fp16 bits, padded
    float* __restrict__ mu,                   // [4096][1000]
    float* __restrict__ sigma_out,            // d_out + NC_TOT
    f32x2* __restrict__ eps2,                 // ws + EPS2_OFF (pre=1 only)
    int pre) {
  const int K = 1024;
  __shared__ unsigned short As[128 * BK];     // 8 KB
  __shared__ unsigned short Bs[64 * BK];      // 4 KB

  int bid = blockIdx.x;
  int id;  bool rng;
  if (pre) { rng = (bid & 1) != 0; id = bid >> 1; }
  else     { rng = false;          id = bid;      }

  int tid  = threadIdx.x;
  int w    = tid >> 6;
  int lane = tid & 63;

  if (rng) {
    // ---- RNG precompute: block id handles n = 4*id .. 4*id+3; wave w owns t = 4w ----
    for (int k = 0; k < 4; k++) {
      int n  = id * 4 + k;
      int cb = n * 1000;
      unsigned ib = (unsigned)((w * 4) * 4096000 + cb) + (unsigned)lane;
      f32x2* base = eps2 + (w * 4096 + n) * 1024 + lane;
#pragma unroll
      for (int j = 0; j < 16; j++) {
        unsigned i0 = ib + (unsigned)(j * 64);
        unsigned o0, o1;
        threefry(i0, i0 + H_HALF, o0, o1);
        f32x2 epsp = normal2p(bits_to_u2(o0, o1));
        unsigned long long bits = __builtin_bit_cast(unsigned long long, epsp);
        __builtin_nontemporal_store(bits, (unsigned long long*)(base + j * 64));
      }
    }
    return;
  }

  // ---- GEMM body (r3 verbatim) ----
  int xcd = id & 7;
  int q9  = id >> 3;                    // 0..127
  int by  = xcd * 4 + (q9 >> 5);        // 0..31
  int bx  = q9 & 31;                    // 0..31

  int wr   = (w >> 1) * 64;             // wave row offset (0/64)
  int wc   = (w & 1) * 32;              // wave col offset (0/32)
  int lrow = lane & 15;
  int kq   = lane >> 4;

  f32x4 acc[4][2];
  for (int i = 0; i < 4; i++)
    for (int j = 0; j < 2; j++) acc[i][j] = (f32x4){0.f, 0.f, 0.f, 0.f};

  int srow = w * 16 + (lane >> 2);
  int scol = (lane & 3) * 8;
  const unsigned short* Ap = Ah + (by * 128 + srow) * K + scol;
  const unsigned short* Bp = Bh + (bx * 64  + srow) * K + scol;   // srow < 64
  unsigned short* lA = As + w * 512;
  unsigned short* lB = Bs + w * 512;

  for (int kk = 0; kk < K; kk += BK) {
    __syncthreads();
    glds16(Ap + kk,          lA);             // A rows 0..63
    glds16(Ap + kk + 64 * K, lA + 2048);      // A rows 64..127
    glds16(Bp + kk,          lB);             // B rows 0..63
    __syncthreads();

    f16x8 a[4], b[2];
    for (int i = 0; i < 4; i++)
      a[i] = *(const f16x8*)(As + (wr + i * 16 + lrow) * BK + kq * 8);
    for (int j = 0; j < 2; j++)
      b[j] = *(const f16x8*)(Bs + (wc + j * 16 + lrow) * BK + kq * 8);
    for (int i = 0; i < 4; i++)
      for (int j = 0; j < 2; j++)
        acc[i][j] = __builtin_amdgcn_mfma_f32_16x16x32_f16(a[i], b[j], acc[i][j], 0, 0, 0);
  }

  // C/D layout: col = lane&15 (N), row = (lane>>4)*4 + reg (M)
  int orow0 = by * 128 + wr + (lane >> 4) * 4;
  int ocol0 = bx * 64 + wc + (lane & 15);
  for (int i = 0; i < 4; i++) {
    for (int j = 0; j < 2; j++) {
      int c = ocol0 + j * 16;
      for (int v = 0; v < 4; v++) {
        int r = orow0 + i * 16 + v;
        float val = acc[i][j][v];
        if (c < 1000)       mu[r * 1000 + c] = val;
        else if (c < 2000)  sigma_out[r * 1000 + (c - 1000)] = __expf(0.5f * val);
      }
    }
  }
}

// ---------------- sampling: r6 structure; it==0 reads precomputed epsp if pre -------
__global__ __launch_bounds__(256, 2) void sample_kernel(
    const float* __restrict__ mu,      // ws
    const float* __restrict__ sigma,   // d_out + NC
    float* __restrict__ out0,          // d_out
    const f32x2* __restrict__ eps2,    // ws + EPS2_OFF
    int pre) {
  int n    = blockIdx.x;
  int tid  = threadIdx.x;
  int lane = tid & 63, w = tid >> 6;
  __shared__ float pbuf[4][1024];

  // exp(mu + sigma*sqrt2*erfinvp) == exp2( mu*L2E + (sigma*sqrt2*L2E)*erfinvp )
  const float L2E    = 1.44269504f;
  const float SQ2L2E = 1.41421356f * 1.44269504f;

  int cb = n * 1000;
  float mu2[16], sg2[16], prob[16];
#pragma unroll
  for (int j = 0; j < 16; j++) {
    int c = j * 64 + lane;
    bool val = (c < 1000);
    mu2[j]  = val ? mu[cb + c] * L2E       : -1e30f;  // exp2(-1e30)==0: pad classes
    sg2[j]  = val ? sigma[cb + c] * SQ2L2E : 0.f;
    prob[j] = 0.f;
  }

  const f32x2* epb = eps2 + (w * 4096 + n) * 1024 + lane;

  f32x2 e[16];
#pragma unroll 1
  for (int it = 0; it < 4; it++) {
    int t = w * 4 + it;
    unsigned ib = (unsigned)(t * 4096000 + cb) + (unsigned)lane;
    f32x2 s = splat2(0.f);
    if (it == 0 && pre) {
      // epsp precomputed during the GEMM (bit-identical values)
#pragma unroll
      for (int j = 0; j < 16; j++) {
        f32x2 epsp = epb[j * 64];
        float ex = __builtin_amdgcn_exp2f(fmaf(sg2[j], epsp.x, mu2[j]));
        float ey = __builtin_amdgcn_exp2f(fmaf(sg2[j], epsp.y, mu2[j]));
        asm volatile("" : "+v"(ex), "+v"(ey));
        e[j] = (f32x2){ex, ey};
        s.x += ex;
        s.y += ey;
      }
    } else {
#pragma unroll
      for (int j = 0; j < 16; j++) {
        unsigned i0 = ib + (unsigned)(j * 64);
        unsigned o0, o1;
        threefry(i0, i0 + H_HALF, o0, o1);
        f32x2 epsp = normal2p(bits_to_u2(o0, o1));
        float ex = __builtin_amdgcn_exp2f(fmaf(sg2[j], epsp.x, mu2[j]));  // sample t
        float ey = __builtin_amdgcn_exp2f(fmaf(sg2[j], epsp.y, mu2[j]));  // sample t+16
        asm volatile("" : "+v"(ex), "+v"(ey));   // pin: forbid recompute of the chain
        e[j] = (f32x2){ex, ey};
        s.x += ex;
        s.y += ey;
      }
    }
#pragma unroll
    for (int m = 1; m < 64; m <<= 1) {
      s.x += __shfl_xor(s.x, m, 64);
      s.y += __shfl_xor(s.y, m, 64);
    }
    float rA = __builtin_amdgcn_rcpf(s.x);
    float rB = __builtin_amdgcn_rcpf(s.y);
#pragma unroll
    for (int j = 0; j < 16; j++)
      prob[j] = fmaf(e[j].x, rA, fmaf(e[j].y, rB, prob[j]));
  }

#pragma unroll
  for (int j = 0; j < 16; j++)
    pbuf[w][j * 64 + lane] = prob[j];
  __syncthreads();
#pragma unroll
  for (int k = 0; k < 4; k++) {
    int c = tid + k * 256;
    if (c < 1000) {
      float sm = pbuf[0][c] + pbuf[1][c] + pbuf[2][c] + pbuf[3][c];
      out0[cb + c] = __builtin_amdgcn_exp2f(sm * (0.03125f * 1.44269504f));
    }
  }
}

// ---------------- launch ----------------
extern "C" void kernel_launch(void* const* d_in, const int* in_sizes, int n_in,
                              void* d_out, int out_size, void* d_ws, size_t ws_size,
                              hipStream_t stream) {
  const float* x = (const float*)d_in[0];   // 4096*1024
  const float* W = (const float*)d_in[1];   // 2000*1024
  float* out = (float*)d_out;               // [mu_out | sigma], each 4096000

  unsigned short* xh = (unsigned short*)d_ws;                        //  8,388,608 B
  unsigned short* wh = (unsigned short*)((char*)d_ws + 8388608);     //  4,194,304 B
  float*          mu = (float*)((char*)d_ws + 12582912);             // 16,384,000 B
  f32x2*        eps2 = (f32x2*)((char*)d_ws + EPS2_OFF);             // 134,217,728 B
  float* sigma = out + NC_TOT;

  int pre = (ws_size >= (size_t)WS_NEED) ? 1 : 0;

  convert_kernel<<<6144, 256, 0, stream>>>(x, W, xh, wh);
  gemm_rng_kernel<<<1024 * (1 + pre), 256, 0, stream>>>(xh, wh, mu, sigma, eps2, pre);
  sample_kernel<<<4096, 256, 0, stream>>>(mu, sigma, out, eps2, pre);
}

// Round 9
// 284.046 us; speedup vs baseline: 1.0910x; 1.0910x over previous
//
#include <hip/hip_runtime.h>

// Problem: N=4096, D=1024, C=1000, T=32
//   h = x @ W^T  (4096 x 2000), mu = h[:, :1000], logvar = h[:, 1000:]
//   sigma = exp(0.5*logvar)
//   eps = jax.random.normal(key(42), (32,4096,1000))  -- threefry2x32, bit-exact
//   prob = mean_t softmax(mu + sigma*eps), out0 = exp(prob), out1 = sigma
//
// r17: r6 known-good everything + ONE change: GEMM BK 32->64 (same 2-barrier sync
// structure, half the K-steps => half the vmcnt(0) barrier drains). r8 lesson banked:
// issue-bound kernels don't overlap (GEMM is 43% VALU-issue, RNG 90% => additive);
// eps2 precompute removed entirely.

typedef __attribute__((ext_vector_type(8))) _Float16 f16x8;
typedef __attribute__((ext_vector_type(4))) float f32x4;
typedef __attribute__((ext_vector_type(2))) float f32x2;

#define NC_TOT  4096000
#define H_HALF  65536000u   // half of T*N*C = 131072000

// ---------------- fp32 -> fp16 (RNE) ----------------
__device__ __forceinline__ unsigned short f2h(float f) {
  _Float16 h = (_Float16)f;
  return __builtin_bit_cast(unsigned short, h);
}

__global__ __launch_bounds__(256) void convert_kernel(
    const float* __restrict__ x, const float* __restrict__ W,
    unsigned short* __restrict__ xh, unsigned short* __restrict__ wh) {
  int qid = blockIdx.x * 256 + threadIdx.x;
  if (qid < 1048576) {                        // x: 4096*1024/4
    float4 v = ((const float4*)x)[qid];
    ((ushort4*)xh)[qid] = make_ushort4(f2h(v.x), f2h(v.y), f2h(v.z), f2h(v.w));
  } else {
    int q = qid - 1048576;                    // padded W quad index, < 524288
    int row = q >> 8;
    ushort4 o;
    if (row < 2000) {
      float4 v = ((const float4*)W)[q];
      o = make_ushort4(f2h(v.x), f2h(v.y), f2h(v.z), f2h(v.w));
    } else {
      o = make_ushort4(0, 0, 0, 0);
    }
    ((ushort4*)wh)[q] = o;
  }
}

// ---------------- fp16 MFMA GEMM: 128x64 tiles, 1024 blocks (4/CU), BK=64 ----------
// Same r3 sync structure (barrier -> stage -> barrier -> compute), 16 K-steps.
// Per iter: 6 glds16 (A rows 0..127 in 4 chunks of 32, B rows 0..63 in 2), then
// 16 MFMA/wave (4x2 acc x 2 k-slices). Totals identical to BK=32; barriers halved.
// MFMA k-order unchanged -> mu/sigma bit-identical.
#define BK 64

typedef __attribute__((address_space(3))) unsigned char lds_byte;
typedef __attribute__((address_space(1))) unsigned char glb_byte;

__device__ __forceinline__ void glds16(const unsigned short* g, unsigned short* l) {
  __builtin_amdgcn_global_load_lds((const glb_byte*)g, (lds_byte*)l, 16, 0, 0);
}

__global__ __launch_bounds__(256) void gemm_kernel(
    const unsigned short* __restrict__ Ah,    // [4096][1024] fp16 bits
    const unsigned short* __restrict__ Bh,    // [2048][1024] fp16 bits, padded
    float* __restrict__ mu,                   // [4096][1000]
    float* __restrict__ sigma_out) {          // d_out + NC_TOT
  const int K = 1024;
  __shared__ unsigned short As[128 * BK];     // 16 KB
  __shared__ unsigned short Bs[64 * BK];      //  8 KB

  int id  = blockIdx.x;                 // 0..1023
  int xcd = id & 7;
  int q9  = id >> 3;                    // 0..127
  int by  = xcd * 4 + (q9 >> 5);        // 0..31
  int bx  = q9 & 31;                    // 0..31

  int tid  = threadIdx.x;
  int w    = tid >> 6;
  int lane = tid & 63;
  int wr   = (w >> 1) * 64;             // wave row offset (0/64)
  int wc   = (w & 1) * 32;              // wave col offset (0/32)
  int lrow = lane & 15;
  int kq   = lane >> 4;

  f32x4 acc[4][2];
  for (int i = 0; i < 4; i++)
    for (int j = 0; j < 2; j++) acc[i][j] = (f32x4){0.f, 0.f, 0.f, 0.f};

  // staging map for [row][64] tiles: wave w covers rows w*8+(lane>>3), cols (lane&7)*8.
  // Each glds16 call stages one 32-row chunk (4 KB/block, 1 KB/wave, LDS-contiguous).
  int srow = w * 8 + (lane >> 3);
  int scol = (lane & 7) * 8;
  const unsigned short* Ap = Ah + (by * 128 + srow) * K + scol;
  const unsigned short* Bp = Bh + (bx * 64  + srow) * K + scol;   // srow < 32
  unsigned short* lA = As + w * 512;    // w*8 rows * 64 cols
  unsigned short* lB = Bs + w * 512;

  for (int kk = 0; kk < K; kk += BK) {
    __syncthreads();
    glds16(Ap + kk,           lA);             // A rows  0..31
    glds16(Ap + kk + 32 * K,  lA + 2048);      // A rows 32..63
    glds16(Ap + kk + 64 * K,  lA + 4096);      // A rows 64..95
    glds16(Ap + kk + 96 * K,  lA + 6144);      // A rows 96..127
    glds16(Bp + kk,           lB);             // B rows  0..31
    glds16(Bp + kk + 32 * K,  lB + 2048);      // B rows 32..63
    __syncthreads();

    f16x8 a[4][2], b[2][2];
    for (int i = 0; i < 4; i++)
      for (int ks = 0; ks < 2; ks++)
        a[i][ks] = *(const f16x8*)(As + (wr + i * 16 + lrow) * BK + ks * 32 + kq * 8);
    for (int j = 0; j < 2; j++)
      for (int ks = 0; ks < 2; ks++)
        b[j][ks] = *(const f16x8*)(Bs + (wc + j * 16 + lrow) * BK + ks * 32 + kq * 8);
    for (int ks = 0; ks < 2; ks++)             // k ascending: bit-identical to BK=32
      for (int i = 0; i < 4; i++)
        for (int j = 0; j < 2; j++)
          acc[i][j] = __builtin_amdgcn_mfma_f32_16x16x32_f16(a[i][ks], b[j][ks], acc[i][j], 0, 0, 0);
  }

  // C/D layout: col = lane&15 (N), row = (lane>>4)*4 + reg (M)
  int orow0 = by * 128 + wr + (lane >> 4) * 4;
  int ocol0 = bx * 64 + wc + (lane & 15);
  for (int i = 0; i < 4; i++) {
    for (int j = 0; j < 2; j++) {
      int c = ocol0 + j * 16;
      for (int v = 0; v < 4; v++) {
        int r = orow0 + i * 16 + v;
        float val = acc[i][j][v];
        if (c < 1000)       mu[r * 1000 + c] = val;
        else if (c < 2000)  sigma_out[r * 1000 + (c - 1000)] = __expf(0.5f * val);
      }
    }
  }
}

// ---------------- threefry2x32, key = (0, 42) ----------------
// rotl forced to single v_alignbit_b32 (rotl(x,r) == rotr(x,32-r)).
__device__ __forceinline__ unsigned rotl_(unsigned x, unsigned r) {
  return __builtin_amdgcn_alignbit(x, x, 32u - r);
}

__device__ __forceinline__ void threefry(unsigned x0, unsigned x1,
                                         unsigned& o0, unsigned& o1) {
  const unsigned ks1 = 42u;
  const unsigned ks2 = 0x1BD11BDAu ^ 42u;
#define TF_RND(r) { x0 += x1; x1 = rotl_(x1, r); x1 ^= x0; }
  x1 += ks1;
  TF_RND(13) TF_RND(15) TF_RND(26) TF_RND(6)
  x0 += ks1;  x1 += ks2 + 1u;
  TF_RND(17) TF_RND(29) TF_RND(16) TF_RND(24)
  x0 += ks2;  x1 += 2u;
  TF_RND(13) TF_RND(15) TF_RND(26) TF_RND(6)
  x1 += ks1 + 3u;
  TF_RND(17) TF_RND(29) TF_RND(16) TF_RND(24)
  x0 += ks1;  x1 += ks2 + 4u;
  TF_RND(13) TF_RND(15) TF_RND(26) TF_RND(6)
  x0 += ks2;  x1 += 5u;
#undef TF_RND
  o0 = x0; o1 = x1;
}

__device__ __forceinline__ f32x2 splat2(float c) { return (f32x2){c, c}; }

// Tail branch of erfinv; returns p*x WITHOUT the sqrt2 factor
// (sqrt2*log2e is folded into the precomputed sigma scale).
__device__ __forceinline__ float erfinv_big_p(float x, float lg) {
  float w = lg * -0.69314718f;
  float v = __fsqrt_rn(w) - 3.0f;
  float p = -0.000200214257f;
  p = fmaf(p, v, 0.000100950558f);
  p = fmaf(p, v, 0.00134934322f);
  p = fmaf(p, v, -0.00367342844f);
  p = fmaf(p, v, 0.00573950773f);
  p = fmaf(p, v, -0.0076224613f);
  p = fmaf(p, v, 0.00943887047f);
  p = fmaf(p, v, 1.00167406f);
  p = fmaf(p, v, 2.83297682f);
  return p * x;
}

// normal WITHOUT the sqrt2 factor: returns p(v)*x (r6 verbatim, passing).
__device__ __forceinline__ f32x2 normal2p(f32x2 x) {
  f32x2 t = __builtin_elementwise_fma(-x, x, splat2(1.0f));
  f32x2 lg;
  lg.x = __builtin_amdgcn_logf(t.x);
  lg.y = __builtin_amdgcn_logf(t.y);
  f32x2 v = __builtin_elementwise_fma(lg, splat2(-0.69314718f), splat2(-2.5f));
  f32x2 p = splat2(2.81022636e-08f);
  p = __builtin_elementwise_fma(p, v, splat2(3.43273939e-07f));
  p = __builtin_elementwise_fma(p, v, splat2(-3.5233877e-06f));
  p = __builtin_elementwise_fma(p, v, splat2(-4.39150654e-06f));
  p = __builtin_elementwise_fma(p, v, splat2(0.00021858087f));
  p = __builtin_elementwise_fma(p, v, splat2(-0.00125372503f));
  p = __builtin_elementwise_fma(p, v, splat2(-0.00417768164f));
  p = __builtin_elementwise_fma(p, v, splat2(0.246640727f));
  p = __builtin_elementwise_fma(p, v, splat2(1.50140941f));
  f32x2 r = p * x;
  bool c0 = lg.x <= -7.2134752f;                 // == (w >= 5), rare (~0.34%/sample)
  bool c1 = lg.y <= -7.2134752f;
  if (__builtin_expect(__ballot(c0 || c1) != 0ull, false)) {
    if (c0) r.x = erfinv_big_p(x.x, lg.x);
    if (c1) r.y = erfinv_big_p(x.y, lg.y);
  }
  return r;
}

__device__ __forceinline__ f32x2 bits_to_u2(unsigned b0, unsigned b1) {
  f32x2 f;
  f.x = __builtin_bit_cast(float, (b0 >> 9) | 0x3f800000u);
  f.y = __builtin_bit_cast(float, (b1 >> 9) | 0x3f800000u);
  f = f - splat2(1.0f);
  return __builtin_elementwise_fma(f, splat2(2.0f), splat2(-0.99999994f));
}

// ---------------- sampling: r6 verbatim (passing, at derated VALU issue floor) -------
__global__ __launch_bounds__(256, 2) void sample_kernel(
    const float* __restrict__ mu,      // ws
    const float* __restrict__ sigma,   // d_out + NC
    float* __restrict__ out0) {        // d_out
  int n    = blockIdx.x;
  int tid  = threadIdx.x;
  int lane = tid & 63, w = tid >> 6;
  __shared__ float pbuf[4][1024];

  // exp(mu + sigma*sqrt2*erfinvp) == exp2( mu*L2E + (sigma*sqrt2*L2E)*erfinvp )
  const float L2E    = 1.44269504f;
  const float SQ2L2E = 1.41421356f * 1.44269504f;

  int cb = n * 1000;
  float mu2[16], sg2[16], prob[16];
#pragma unroll
  for (int j = 0; j < 16; j++) {
    int c = j * 64 + lane;
    bool val = (c < 1000);
    mu2[j]  = val ? mu[cb + c] * L2E       : -1e30f;  // exp2(-1e30)==0: pad classes
    sg2[j]  = val ? sigma[cb + c] * SQ2L2E : 0.f;
    prob[j] = 0.f;
  }

  f32x2 e[16];
#pragma unroll 1
  for (int it = 0; it < 4; it++) {
    int t = w * 4 + it;
    unsigned ib = (unsigned)(t * 4096000 + cb) + (unsigned)lane;
    f32x2 s = splat2(0.f);
#pragma unroll
    for (int j = 0; j < 16; j++) {
      unsigned i0 = ib + (unsigned)(j * 64);
      unsigned o0, o1;
      threefry(i0, i0 + H_HALF, o0, o1);
      f32x2 epsp = normal2p(bits_to_u2(o0, o1));
      float ex = __builtin_amdgcn_exp2f(fmaf(sg2[j], epsp.x, mu2[j]));  // sample t
      float ey = __builtin_amdgcn_exp2f(fmaf(sg2[j], epsp.y, mu2[j]));  // sample t+16
      asm volatile("" : "+v"(ex), "+v"(ey));   // pin: forbid recompute of the chain
      e[j] = (f32x2){ex, ey};
      s.x += ex;
      s.y += ey;
    }
#pragma unroll
    for (int m = 1; m < 64; m <<= 1) {
      s.x += __shfl_xor(s.x, m, 64);
      s.y += __shfl_xor(s.y, m, 64);
    }
    float rA = __builtin_amdgcn_rcpf(s.x);
    float rB = __builtin_amdgcn_rcpf(s.y);
#pragma unroll
    for (int j = 0; j < 16; j++)
      prob[j] = fmaf(e[j].x, rA, fmaf(e[j].y, rB, prob[j]));
  }

#pragma unroll
  for (int j = 0; j < 16; j++)
    pbuf[w][j * 64 + lane] = prob[j];
  __syncthreads();
#pragma unroll
  for (int k = 0; k < 4; k++) {
    int c = tid + k * 256;
    if (c < 1000) {
      float sm = pbuf[0][c] + pbuf[1][c] + pbuf[2][c] + pbuf[3][c];
      out0[cb + c] = __builtin_amdgcn_exp2f(sm * (0.03125f * 1.44269504f));
    }
  }
}

// ---------------- launch ----------------
extern "C" void kernel_launch(void* const* d_in, const int* in_sizes, int n_in,
                              void* d_out, int out_size, void* d_ws, size_t ws_size,
                              hipStream_t stream) {
  const float* x = (const float*)d_in[0];   // 4096*1024
  const float* W = (const float*)d_in[1];   // 2000*1024
  float* out = (float*)d_out;               // [mu_out | sigma], each 4096000

  unsigned short* xh = (unsigned short*)d_ws;                        //  8,388,608 B
  unsigned short* wh = (unsigned short*)((char*)d_ws + 8388608);     //  4,194,304 B
  float*          mu = (float*)((char*)d_ws + 12582912);             // 16,384,000 B
  float* sigma = out + NC_TOT;

  convert_kernel<<<6144, 256, 0, stream>>>(x, W, xh, wh);
  gemm_kernel<<<1024, 256, 0, stream>>>(xh, wh, mu, sigma);
  sample_kernel<<<4096, 256, 0, stream>>>(mu, sigma, out);
}

// Round 10
// 282.627 us; speedup vs baseline: 1.0965x; 1.0050x over previous
//
#include <hip/hip_runtime.h>

// Problem: N=4096, D=1024, C=1000, T=32
//   h = x @ W^T  (4096 x 2000), mu = h[:, :1000], logvar = h[:, 1000:]
//   sigma = exp(0.5*logvar)
//   eps = jax.random.normal(key(42), (32,4096,1000))  -- threefry2x32, bit-exact
//   prob = mean_t softmax(mu + sigma*eps), out0 = exp(prob), out1 = sigma
//
// r18: EXACT revert to the r6 best-measured configuration (280.5 us). Session
// findings: sample is at its VALU issue floor (96% busy, slot count closes with
// static minimum); GEMM structural edits x3 all neutral (implicit wave overlap at
// 4 blocks/CU already covers them); RNG/GEMM fusion additive (both issue-bound).

typedef __attribute__((ext_vector_type(8))) _Float16 f16x8;
typedef __attribute__((ext_vector_type(4))) float f32x4;
typedef __attribute__((ext_vector_type(2))) float f32x2;

#define NC_TOT  4096000
#define H_HALF  65536000u   // half of T*N*C = 131072000

// ---------------- fp32 -> fp16 (RNE) ----------------
__device__ __forceinline__ unsigned short f2h(float f) {
  _Float16 h = (_Float16)f;
  return __builtin_bit_cast(unsigned short, h);
}

__global__ __launch_bounds__(256) void convert_kernel(
    const float* __restrict__ x, const float* __restrict__ W,
    unsigned short* __restrict__ xh, unsigned short* __restrict__ wh) {
  int qid = blockIdx.x * 256 + threadIdx.x;
  if (qid < 1048576) {                        // x: 4096*1024/4
    float4 v = ((const float4*)x)[qid];
    ((ushort4*)xh)[qid] = make_ushort4(f2h(v.x), f2h(v.y), f2h(v.z), f2h(v.w));
  } else {
    int q = qid - 1048576;                    // padded W quad index, < 524288
    int row = q >> 8;
    ushort4 o;
    if (row < 2000) {
      float4 v = ((const float4*)W)[q];
      o = make_ushort4(f2h(v.x), f2h(v.y), f2h(v.z), f2h(v.w));
    } else {
      o = make_ushort4(0, 0, 0, 0);
    }
    ((ushort4*)wh)[q] = o;
  }
}

// ---------------- fp16 MFMA GEMM: 128x64 tiles, 1024 blocks (4/CU) ----------------
// r3/r6 verbatim known-good loop.
#define BK 32

typedef __attribute__((address_space(3))) unsigned char lds_byte;
typedef __attribute__((address_space(1))) unsigned char glb_byte;

__device__ __forceinline__ void glds16(const unsigned short* g, unsigned short* l) {
  __builtin_amdgcn_global_load_lds((const glb_byte*)g, (lds_byte*)l, 16, 0, 0);
}

__global__ __launch_bounds__(256) void gemm_kernel(
    const unsigned short* __restrict__ Ah,    // [4096][1024] fp16 bits
    const unsigned short* __restrict__ Bh,    // [2048][1024] fp16 bits, padded
    float* __restrict__ mu,                   // [4096][1000]
    float* __restrict__ sigma_out) {          // d_out + NC_TOT
  const int K = 1024;
  __shared__ unsigned short As[128 * BK];     // 8 KB
  __shared__ unsigned short Bs[64 * BK];      // 4 KB

  int id  = blockIdx.x;                 // 0..1023
  int xcd = id & 7;
  int q9  = id >> 3;                    // 0..127
  int by  = xcd * 4 + (q9 >> 5);        // 0..31
  int bx  = q9 & 31;                    // 0..31

  int tid  = threadIdx.x;
  int w    = tid >> 6;
  int lane = tid & 63;
  int wr   = (w >> 1) * 64;             // wave row offset (0/64)
  int wc   = (w & 1) * 32;              // wave col offset (0/32)
  int lrow = lane & 15;
  int kq   = lane >> 4;

  f32x4 acc[4][2];
  for (int i = 0; i < 4; i++)
    for (int j = 0; j < 2; j++) acc[i][j] = (f32x4){0.f, 0.f, 0.f, 0.f};

  int srow = w * 16 + (lane >> 2);
  int scol = (lane & 3) * 8;
  const unsigned short* Ap = Ah + (by * 128 + srow) * K + scol;
  const unsigned short* Bp = Bh + (bx * 64  + srow) * K + scol;   // srow < 64
  unsigned short* lA = As + w * 512;
  unsigned short* lB = Bs + w * 512;

  for (int kk = 0; kk < K; kk += BK) {
    __syncthreads();
    glds16(Ap + kk,          lA);             // A rows 0..63
    glds16(Ap + kk + 64 * K, lA + 2048);      // A rows 64..127
    glds16(Bp + kk,          lB);             // B rows 0..63
    __syncthreads();

    f16x8 a[4], b[2];
    for (int i = 0; i < 4; i++)
      a[i] = *(const f16x8*)(As + (wr + i * 16 + lrow) * BK + kq * 8);
    for (int j = 0; j < 2; j++)
      b[j] = *(const f16x8*)(Bs + (wc + j * 16 + lrow) * BK + kq * 8);
    for (int i = 0; i < 4; i++)
      for (int j = 0; j < 2; j++)
        acc[i][j] = __builtin_amdgcn_mfma_f32_16x16x32_f16(a[i], b[j], acc[i][j], 0, 0, 0);
  }

  // C/D layout: col = lane&15 (N), row = (lane>>4)*4 + reg (M)
  int orow0 = by * 128 + wr + (lane >> 4) * 4;
  int ocol0 = bx * 64 + wc + (lane & 15);
  for (int i = 0; i < 4; i++) {
    for (int j = 0; j < 2; j++) {
      int c = ocol0 + j * 16;
      for (int v = 0; v < 4; v++) {
        int r = orow0 + i * 16 + v;
        float val = acc[i][j][v];
        if (c < 1000)       mu[r * 1000 + c] = val;
        else if (c < 2000)  sigma_out[r * 1000 + (c - 1000)] = __expf(0.5f * val);
      }
    }
  }
}

// ---------------- threefry2x32, key = (0, 42) ----------------
// rotl forced to single v_alignbit_b32 (rotl(x,r) == rotr(x,32-r)).
__device__ __forceinline__ unsigned rotl_(unsigned x, unsigned r) {
  return __builtin_amdgcn_alignbit(x, x, 32u - r);
}

__device__ __forceinline__ void threefry(unsigned x0, unsigned x1,
                                         unsigned& o0, unsigned& o1) {
  const unsigned ks1 = 42u;
  const unsigned ks2 = 0x1BD11BDAu ^ 42u;
#define TF_RND(r) { x0 += x1; x1 = rotl_(x1, r); x1 ^= x0; }
  x1 += ks1;
  TF_RND(13) TF_RND(15) TF_RND(26) TF_RND(6)
  x0 += ks1;  x1 += ks2 + 1u;
  TF_RND(17) TF_RND(29) TF_RND(16) TF_RND(24)
  x0 += ks2;  x1 += 2u;
  TF_RND(13) TF_RND(15) TF_RND(26) TF_RND(6)
  x1 += ks1 + 3u;
  TF_RND(17) TF_RND(29) TF_RND(16) TF_RND(24)
  x0 += ks1;  x1 += ks2 + 4u;
  TF_RND(13) TF_RND(15) TF_RND(26) TF_RND(6)
  x0 += ks2;  x1 += 5u;
#undef TF_RND
  o0 = x0; o1 = x1;
}

__device__ __forceinline__ f32x2 splat2(float c) { return (f32x2){c, c}; }

// Tail branch of erfinv; returns p*x WITHOUT the sqrt2 factor
// (sqrt2*log2e is folded into the precomputed sigma scale).
__device__ __forceinline__ float erfinv_big_p(float x, float lg) {
  float w = lg * -0.69314718f;
  float v = __fsqrt_rn(w) - 3.0f;
  float p = -0.000200214257f;
  p = fmaf(p, v, 0.000100950558f);
  p = fmaf(p, v, 0.00134934322f);
  p = fmaf(p, v, -0.00367342844f);
  p = fmaf(p, v, 0.00573950773f);
  p = fmaf(p, v, -0.0076224613f);
  p = fmaf(p, v, 0.00943887047f);
  p = fmaf(p, v, 1.00167406f);
  p = fmaf(p, v, 2.83297682f);
  return p * x;
}

// normal WITHOUT the sqrt2 factor: returns p(v)*x (r6 verbatim, passing).
__device__ __forceinline__ f32x2 normal2p(f32x2 x) {
  f32x2 t = __builtin_elementwise_fma(-x, x, splat2(1.0f));
  f32x2 lg;
  lg.x = __builtin_amdgcn_logf(t.x);
  lg.y = __builtin_amdgcn_logf(t.y);
  f32x2 v = __builtin_elementwise_fma(lg, splat2(-0.69314718f), splat2(-2.5f));
  f32x2 p = splat2(2.81022636e-08f);
  p = __builtin_elementwise_fma(p, v, splat2(3.43273939e-07f));
  p = __builtin_elementwise_fma(p, v, splat2(-3.5233877e-06f));
  p = __builtin_elementwise_fma(p, v, splat2(-4.39150654e-06f));
  p = __builtin_elementwise_fma(p, v, splat2(0.00021858087f));
  p = __builtin_elementwise_fma(p, v, splat2(-0.00125372503f));
  p = __builtin_elementwise_fma(p, v, splat2(-0.00417768164f));
  p = __builtin_elementwise_fma(p, v, splat2(0.246640727f));
  p = __builtin_elementwise_fma(p, v, splat2(1.50140941f));
  f32x2 r = p * x;
  bool c0 = lg.x <= -7.2134752f;                 // == (w >= 5), rare (~0.34%/sample)
  bool c1 = lg.y <= -7.2134752f;
  if (__builtin_expect(__ballot(c0 || c1) != 0ull, false)) {
    if (c0) r.x = erfinv_big_p(x.x, lg.x);
    if (c1) r.y = erfinv_big_p(x.y, lg.y);
  }
  return r;
}

__device__ __forceinline__ f32x2 bits_to_u2(unsigned b0, unsigned b1) {
  f32x2 f;
  f.x = __builtin_bit_cast(float, (b0 >> 9) | 0x3f800000u);
  f.y = __builtin_bit_cast(float, (b1 >> 9) | 0x3f800000u);
  f = f - splat2(1.0f);
  return __builtin_elementwise_fma(f, splat2(2.0f), splat2(-0.99999994f));
}

// ---------------- sampling: r6 verbatim (passing, at derated VALU issue floor) -------
__global__ __launch_bounds__(256, 2) void sample_kernel(
    const float* __restrict__ mu,      // ws
    const float* __restrict__ sigma,   // d_out + NC
    float* __restrict__ out0) {        // d_out
  int n    = blockIdx.x;
  int tid  = threadIdx.x;
  int lane = tid & 63, w = tid >> 6;
  __shared__ float pbuf[4][1024];

  // exp(mu + sigma*sqrt2*erfinvp) == exp2( mu*L2E + (sigma*sqrt2*L2E)*erfinvp )
  const float L2E    = 1.44269504f;
  const float SQ2L2E = 1.41421356f * 1.44269504f;

  int cb = n * 1000;
  float mu2[16], sg2[16], prob[16];
#pragma unroll
  for (int j = 0; j < 16; j++) {
    int c = j * 64 + lane;
    bool val = (c < 1000);
    mu2[j]  = val ? mu[cb + c] * L2E       : -1e30f;  // exp2(-1e30)==0: pad classes
    sg2[j]  = val ? sigma[cb + c] * SQ2L2E : 0.f;
    prob[j] = 0.f;
  }

  f32x2 e[16];
#pragma unroll 1
  for (int it = 0; it < 4; it++) {
    int t = w * 4 + it;
    unsigned ib = (unsigned)(t * 4096000 + cb) + (unsigned)lane;
    f32x2 s = splat2(0.f);
#pragma unroll
    for (int j = 0; j < 16; j++) {
      unsigned i0 = ib + (unsigned)(j * 64);
      unsigned o0, o1;
      threefry(i0, i0 + H_HALF, o0, o1);
      f32x2 epsp = normal2p(bits_to_u2(o0, o1));
      float ex = __builtin_amdgcn_exp2f(fmaf(sg2[j], epsp.x, mu2[j]));  // sample t
      float ey = __builtin_amdgcn_exp2f(fmaf(sg2[j], epsp.y, mu2[j]));  // sample t+16
      asm volatile("" : "+v"(ex), "+v"(ey));   // pin: forbid recompute of the chain
      e[j] = (f32x2){ex, ey};
      s.x += ex;
      s.y += ey;
    }
#pragma unroll
    for (int m = 1; m < 64; m <<= 1) {
      s.x += __shfl_xor(s.x, m, 64);
      s.y += __shfl_xor(s.y, m, 64);
    }
    float rA = __builtin_amdgcn_rcpf(s.x);
    float rB = __builtin_amdgcn_rcpf(s.y);
#pragma unroll
    for (int j = 0; j < 16; j++)
      prob[j] = fmaf(e[j].x, rA, fmaf(e[j].y, rB, prob[j]));
  }

#pragma unroll
  for (int j = 0; j < 16; j++)
    pbuf[w][j * 64 + lane] = prob[j];
  __syncthreads();
#pragma unroll
  for (int k = 0; k < 4; k++) {
    int c = tid + k * 256;
    if (c < 1000) {
      float sm = pbuf[0][c] + pbuf[1][c] + pbuf[2][c] + pbuf[3][c];
      out0[cb + c] = __builtin_amdgcn_exp2f(sm * (0.03125f * 1.44269504f));
    }
  }
}

// ---------------- launch ----------------
extern "C" void kernel_launch(void* const* d_in, const int* in_sizes, int n_in,
                              void* d_out, int out_size, void* d_ws, size_t ws_size,
                              hipStream_t stream) {
  const float* x = (const float*)d_in[0];   // 4096*1024
  const float* W = (const float*)d_in[1];   // 2000*1024
  float* out = (float*)d_out;               // [mu_out | sigma], each 4096000

  unsigned short* xh = (unsigned short*)d_ws;                        //  8,388,608 B
  unsigned short* wh = (unsigned short*)((char*)d_ws + 8388608);     //  4,194,304 B
  float*          mu = (float*)((char*)d_ws + 12582912);             // 16,384,000 B
  float* sigma = out + NC_TOT;

  convert_kernel<<<6144, 256, 0, stream>>>(x, W, xh, wh);
  gemm_kernel<<<1024, 256, 0, stream>>>(xh, wh, mu, sigma);
  sample_kernel<<<4096, 256, 0, stream>>>(mu, sigma, out);
}